// Round 4
// baseline (1188.430 us; speedup 1.0000x reference)
//
#include <hip/hip_runtime.h>
#include <hip/hip_cooperative_groups.h>
#include <math.h>

namespace cg = cooperative_groups;

#define B_SZ   256
#define D_IN   2048
#define HID    2048
#define NSEG   10
#define D_CTX  1024
#define OUT_N  100
#define KWIN   102
#define CAPS   128   // per-1024-chunk compaction cap (mean 51.2, +11 sigma safe)

typedef float f32x4 __attribute__((ext_vector_type(4)));

// non-temporal 16B load: weight/mask streams must not evict L2-resident activations
__device__ __forceinline__ f32x4 ntld4(const float* p) {
  return __builtin_nontemporal_load((const f32x4*)p);
}

// ---------- sortable-key helpers for exact fp32 top-k ----------
__device__ __forceinline__ unsigned f2key(float f) {
  unsigned b = __float_as_uint(f);
  return (b & 0x80000000u) ? ~b : (b | 0x80000000u);
}
__device__ __forceinline__ float key2f(unsigned k) {
  return (k & 0x80000000u) ? __uint_as_float(k & 0x7FFFFFFFu) : __uint_as_float(~k);
}

// ---------- shared-memory union: one allocation serves all phases ----------
union SMem {
  struct { float2 pairs[4][CAPS]; float exch[2][64][21]; } dd;   // 14848 B
  struct { float tile[32][33]; } tp;                             //  4224 B
  struct { int hist[256]; int sfx[256]; unsigned pref; int rem;
           float hrow[HID]; float red[256]; } tk;                // 11272 B
};

// ---------- phase helpers ----------

// transpose x:[256][2048]->xT[2048][256] and ctx:[256][1024]->ctxT[1024][256]
__device__ void transpose_phase(SMem& sm, const float* __restrict__ xsrc, float* __restrict__ xdst,
                                const float* __restrict__ csrc, float* __restrict__ cdst) {
  int bid = blockIdx.x;
  const int NX = (D_IN / 32) * (B_SZ / 32);  // 512
  const int NC = (D_CTX / 32) * (B_SZ / 32); // 256
  if (bid >= NX + NC) return;
  const float* src; float* dst; int cols;
  if (bid < NX) { src = xsrc; dst = xdst; cols = D_IN; }
  else { bid -= NX; src = csrc; dst = cdst; cols = D_CTX; }
  int nbx = cols / 32;
  int bx = bid % nbx, by = bid / nbx;
  int c0 = bx * 32, r0 = by * 32;
  int tx = threadIdx.x & 31, ty = threadIdx.x >> 5;
  for (int i = ty; i < 32; i += 8)
    sm.tp.tile[i][tx] = src[(r0 + i) * cols + (c0 + tx)];
  __syncthreads();
  for (int i = ty; i < 32; i += 8)
    dst[(c0 + i) * B_SZ + (r0 + tx)] = sm.tp.tile[tx][i];
}

// issue-only prefetch of a 1024-float (w,m) chunk into registers
__device__ __forceinline__ void load_wm(const float* __restrict__ wrow,
                                        const float* __restrict__ mrow,
                                        f32x4 w[4], f32x4 m[4]) {
  const int t = threadIdx.x & 63;
#pragma unroll
  for (int i = 0; i < 4; ++i) {
    w[i] = ntld4(wrow + 4 * (t + 64 * i));
    m[i] = ntld4(mrow + 4 * (t + 64 * i));
  }
}

// ballot-compact prefetched regs into (w, c+coff) pairs in LDS; wave-local
__device__ __forceinline__ int store_pairs_regs(const f32x4 w[4], const f32x4 m[4],
                                                int coff, float2* pairs) {
  const int t = threadIdx.x & 63;
  const unsigned long long below = (1ull << t) - 1ull;
  __builtin_amdgcn_wave_barrier();   // don't migrate writes above prior pair reads
  int base = 0;
#pragma unroll
  for (int i = 0; i < 4; ++i) {
    const int c = ((t + 64 * i) << 2) + coff;
    const float wv[4] = {w[i].x, w[i].y, w[i].z, w[i].w};
    const float mv[4] = {m[i].x, m[i].y, m[i].z, m[i].w};
#pragma unroll
    for (int j = 0; j < 4; ++j) {
      bool nz = (mv[j] != 0.f);
      unsigned long long bal = __ballot(nz);
      if (nz) {
        int pos = base + (int)__popcll(bal & below);
        if (pos < CAPS) pairs[pos] = make_float2(wv[j], __int_as_float(c + j));
      }
      base += (int)__popcll(bal);
    }
  }
  __builtin_amdgcn_wave_barrier();
  return base > CAPS ? CAPS : base;
}

// stream+compact (no prefetch) — used by ff2
__device__ __forceinline__ int compact_pairs_1024(const float* __restrict__ wrow,
                                                  const float* __restrict__ mrow,
                                                  int coff, float2* pairs) {
  f32x4 w[4], m[4];
  load_wm(wrow, mrow, w, m);
  return store_pairs_regs(w, m, coff, pairs);
}

// ---------- sparse dot, unroll-8 (8 outstanding 1KB loads/wave) ----------
__device__ __forceinline__ void gather_dot(const float* __restrict__ src,
                                           const float2* pairs, int cnt,
                                           int t4, float out4[4]) {
  float acc[4][4];
#pragma unroll
  for (int s = 0; s < 4; ++s)
#pragma unroll
    for (int i = 0; i < 4; ++i) acc[s][i] = 0.f;
  int j = 0;
  for (; j + 8 <= cnt; j += 8) {
#pragma unroll
    for (int s = 0; s < 8; ++s) {
      float2 p = pairs[j + s];
      const f32x4 cv = *(const f32x4*)(src + (__float_as_int(p.y) << 8) + t4);
      acc[s & 3][0] += cv.x * p.x; acc[s & 3][1] += cv.y * p.x;
      acc[s & 3][2] += cv.z * p.x; acc[s & 3][3] += cv.w * p.x;
    }
  }
  for (; j < cnt; ++j) {
    float2 p = pairs[j];
    const f32x4 cv = *(const f32x4*)(src + (__float_as_int(p.y) << 8) + t4);
    acc[0][0] += cv.x * p.x; acc[0][1] += cv.y * p.x;
    acc[0][2] += cv.z * p.x; acc[0][3] += cv.w * p.x;
  }
#pragma unroll
  for (int i = 0; i < 4; ++i)
    out4[i] = (acc[0][i] + acc[1][i]) + (acc[2][i] + acc[3][i]);
}

// ---------- P1: dendrites(L1+L2) + FF1, 11 uniform chunks per wave ----------
// Block owns units {2b, 2b+1}; wave (pidx,half): L1 unit segs [5h,5h+5) + FF1 half-row,
// then L2 unit segs [5h,5h+5). One barrier at end; halves combined via LDS exch.
__device__ void dendff_phase(SMem& sm,
    const float* __restrict__ W1, const float* __restrict__ maskW1, const float* __restrict__ b1,
    const float* __restrict__ segW1, const float* __restrict__ maskS1,
    const float* __restrict__ segW2, const float* __restrict__ maskS2,
    const float* __restrict__ xT, const float* __restrict__ ctxT,
    float* __restrict__ y1T, float* __restrict__ gate2T) {
  const int wave = threadIdx.x >> 6;
  const int t = threadIdx.x & 63, t4 = t * 4;
  const int pidx = wave >> 1;
  const int half = wave & 1;
  const int uu = blockIdx.x * 2 + pidx;   // unit index for BOTH layers (rows uu and 2048+uu)
  float2* pairs = sm.dd.pairs[wave];

  const float* segWA  = segW1 + (size_t)uu * NSEG * D_CTX + (size_t)half * 5 * D_CTX;
  const float* maskSA = maskS1 + (size_t)uu * NSEG * D_CTX + (size_t)half * 5 * D_CTX;
  const float* segWB  = segW2 + (size_t)uu * NSEG * D_CTX + (size_t)half * 5 * D_CTX;
  const float* maskSB = maskS2 + (size_t)uu * NSEG * D_CTX + (size_t)half * 5 * D_CTX;
  const float* ffW = W1 + (size_t)uu * D_IN + half * 1024;
  const float* ffM = maskW1 + (size_t)uu * D_IN + half * 1024;

  float bestA0[4] = {-1.f, -1.f, -1.f, -1.f}, chosen0[4] = {0.f, 0.f, 0.f, 0.f};
  float bestA1[4] = {-1.f, -1.f, -1.f, -1.f}, chosen1[4] = {0.f, 0.f, 0.f, 0.f};
  float ffp[4] = {0.f, 0.f, 0.f, 0.f};

  f32x4 w[4], m[4];
  load_wm(segWA, maskSA, w, m);
#pragma unroll 1
  for (int k = 0; k < 11; ++k) {
    const int coff = (k == 5) ? half * 1024 : 0;
    int cnt = store_pairs_regs(w, m, coff, pairs);   // consumes prefetched regs
    if (k + 1 < 11) {                                // issue-only prefetch of next chunk
      const int kn = k + 1;
      const float* wp = (kn < 5) ? segWA + kn * D_CTX
                       : (kn == 5) ? ffW : segWB + (kn - 6) * D_CTX;
      const float* mp = (kn < 5) ? maskSA + kn * D_CTX
                       : (kn == 5) ? ffM : maskSB + (kn - 6) * D_CTX;
      load_wm(wp, mp, w, m);
    }
    float d[4];
    gather_dot((k == 5) ? xT : ctxT, pairs, cnt, t4, d);
    if (k == 5) {
#pragma unroll
      for (int i = 0; i < 4; ++i) ffp[i] = d[i];
    } else if (k < 5) {
#pragma unroll
      for (int i = 0; i < 4; ++i) {
        float a = fabsf(d[i]);
        if (a > bestA0[i]) { bestA0[i] = a; chosen0[i] = d[i]; }  // strict > = first occurrence
      }
    } else {
#pragma unroll
      for (int i = 0; i < 4; ++i) {
        float a = fabsf(d[i]);
        if (a > bestA1[i]) { bestA1[i] = a; chosen1[i] = d[i]; }
      }
    }
  }

  if (half) {
#pragma unroll
    for (int i = 0; i < 4; ++i) {
      sm.dd.exch[pidx][t][i]      = bestA0[i];
      sm.dd.exch[pidx][t][4 + i]  = chosen0[i];
      sm.dd.exch[pidx][t][8 + i]  = ffp[i];
      sm.dd.exch[pidx][t][12 + i] = bestA1[i];
      sm.dd.exch[pidx][t][16 + i] = chosen1[i];
    }
  }
  __syncthreads();
  if (!half) {
#pragma unroll
    for (int i = 0; i < 4; ++i) {
      if (sm.dd.exch[pidx][t][i] > bestA0[i])      chosen0[i] = sm.dd.exch[pidx][t][4 + i];
      ffp[i] += sm.dd.exch[pidx][t][8 + i];
      if (sm.dd.exch[pidx][t][12 + i] > bestA1[i]) chosen1[i] = sm.dd.exch[pidx][t][16 + i];
    }
    float bb = b1[uu];
    float4 o;
    o.x = (ffp[0] + bb) / (1.f + expf(-chosen0[0]));
    o.y = (ffp[1] + bb) / (1.f + expf(-chosen0[1]));
    o.z = (ffp[2] + bb) / (1.f + expf(-chosen0[2]));
    o.w = (ffp[3] + bb) / (1.f + expf(-chosen0[3]));
    *(float4*)(y1T + (size_t)uu * B_SZ + t4) = o;
    float4 g;
    g.x = 1.f / (1.f + expf(-chosen1[0]));
    g.y = 1.f / (1.f + expf(-chosen1[1]));
    g.z = 1.f / (1.f + expf(-chosen1[2]));
    g.w = 1.f / (1.f + expf(-chosen1[3]));
    *(float4*)(gate2T + (size_t)uu * B_SZ + t4) = g;
  }
}

// ---------- P3: FF2, block owns units {2b,2b+1}, 2 waves/unit (half-row each) ----------
__device__ void ff2_phase(SMem& sm,
    const float* __restrict__ W2, const float* __restrict__ maskW2, const float* __restrict__ b2,
    const float* __restrict__ h1T, const float* __restrict__ gate2T, float* __restrict__ y2T) {
  const int wave = threadIdx.x >> 6;
  const int t = threadIdx.x & 63, t4 = t * 4;
  const int pidx = wave >> 1, half = wave & 1;
  const int u = blockIdx.x * 2 + pidx;
  float2* pairs = sm.dd.pairs[wave];
  const int off = half * 1024;
  int cnt = compact_pairs_1024(W2 + (size_t)u * HID + off,
                               maskW2 + (size_t)u * HID + off, off, pairs);
  float acc[4];
  gather_dot(h1T, pairs, cnt, t4, acc);
  if (half) {
#pragma unroll
    for (int i = 0; i < 4; ++i) sm.dd.exch[pidx][t][i] = acc[i];
  }
  __syncthreads();
  if (!half) {
#pragma unroll
    for (int i = 0; i < 4; ++i) acc[i] += sm.dd.exch[pidx][t][i];
    float bb = b2[u];
    float4 g = *(const float4*)(gate2T + (size_t)u * B_SZ + t4);
    float4 o;
    o.x = (acc[0] + bb) * g.x; o.y = (acc[1] + bb) * g.y;
    o.z = (acc[2] + bb) * g.z; o.w = (acc[3] + bb) * g.w;
    *(float4*)(y2T + (size_t)u * B_SZ + t4) = o;
  }
}

// ---------- P2: exact top-K per batch column (radix select, stable ties), in place ----------
__device__ void topk_phase(SMem& sm, const float* __restrict__ yT, float* __restrict__ dst) {
  const int b = blockIdx.x, t = threadIdx.x;
  unsigned myk[8];
#pragma unroll
  for (int i = 0; i < 8; ++i)
    myk[i] = f2key(yT[(size_t)(t * 8 + i) * B_SZ + b]);
  unsigned pref = 0;
  int rem = KWIN;
  for (int shift = 24; shift >= 0; shift -= 8) {
    sm.tk.hist[t] = 0;
    __syncthreads();
    unsigned hiMask = (shift == 24) ? 0u : (0xFFFFFFFFu << (shift + 8));
#pragma unroll
    for (int i = 0; i < 8; ++i) {
      unsigned k = myk[i];
      if ((k & hiMask) == pref) atomicAdd(&sm.tk.hist[(k >> shift) & 255], 1);
    }
    __syncthreads();
    sm.tk.sfx[t] = sm.tk.hist[t];
    __syncthreads();
    for (int off = 1; off < 256; off <<= 1) {
      int add = (t + off < 256) ? sm.tk.sfx[t + off] : 0;
      __syncthreads();
      sm.tk.sfx[t] += add;
      __syncthreads();
    }
    int s_incl = sm.tk.sfx[t];
    int s_excl = (t == 255) ? 0 : sm.tk.sfx[t + 1];
    if (s_incl >= rem && s_excl < rem) {
      sm.tk.pref = pref | (((unsigned)t) << shift);
      sm.tk.rem = rem - s_excl;
    }
    __syncthreads();
    pref = sm.tk.pref;
    rem = sm.tk.rem;
    __syncthreads();
  }
  int eq = 0;
#pragma unroll
  for (int i = 0; i < 8; ++i) eq += (myk[i] == pref) ? 1 : 0;
  sm.tk.sfx[t] = eq;
  __syncthreads();
  for (int off = 1; off < 256; off <<= 1) {
    int add = (t >= off) ? sm.tk.sfx[t - off] : 0;
    __syncthreads();
    sm.tk.sfx[t] += add;
    __syncthreads();
  }
  int excl = sm.tk.sfx[t] - eq;
  int taken = 0;
#pragma unroll
  for (int i = 0; i < 8; ++i) {
    unsigned k = myk[i];
    bool keep;
    if (k > pref) keep = true;
    else if (k == pref) { keep = (excl + taken) < rem; taken++; }
    else keep = false;
    float f = keep ? key2f(k) : 0.f;
    dst[(size_t)(t * 8 + i) * B_SZ + b] = f;
  }
}

// ---------- P4: top-K(y2) fused with Dale output head ----------
__device__ void topkout_phase(SMem& sm, const float* __restrict__ yT,
                              const float* __restrict__ Wex, const float* __restrict__ Wix,
                              const float* __restrict__ Wei, const float* __restrict__ bo,
                              float* __restrict__ out) {
  const int b = blockIdx.x, t = threadIdx.x;
  unsigned myk[8];
#pragma unroll
  for (int i = 0; i < 8; ++i)
    myk[i] = f2key(yT[(size_t)(t * 8 + i) * B_SZ + b]);
  unsigned pref = 0;
  int rem = KWIN;
  for (int shift = 24; shift >= 0; shift -= 8) {
    sm.tk.hist[t] = 0;
    __syncthreads();
    unsigned hiMask = (shift == 24) ? 0u : (0xFFFFFFFFu << (shift + 8));
#pragma unroll
    for (int i = 0; i < 8; ++i) {
      unsigned k = myk[i];
      if ((k & hiMask) == pref) atomicAdd(&sm.tk.hist[(k >> shift) & 255], 1);
    }
    __syncthreads();
    sm.tk.sfx[t] = sm.tk.hist[t];
    __syncthreads();
    for (int off = 1; off < 256; off <<= 1) {
      int add = (t + off < 256) ? sm.tk.sfx[t + off] : 0;
      __syncthreads();
      sm.tk.sfx[t] += add;
      __syncthreads();
    }
    int s_incl = sm.tk.sfx[t];
    int s_excl = (t == 255) ? 0 : sm.tk.sfx[t + 1];
    if (s_incl >= rem && s_excl < rem) {
      sm.tk.pref = pref | (((unsigned)t) << shift);
      sm.tk.rem = rem - s_excl;
    }
    __syncthreads();
    pref = sm.tk.pref;
    rem = sm.tk.rem;
    __syncthreads();
  }
  int eq = 0;
#pragma unroll
  for (int i = 0; i < 8; ++i) eq += (myk[i] == pref) ? 1 : 0;
  sm.tk.sfx[t] = eq;
  __syncthreads();
  for (int off = 1; off < 256; off <<= 1) {
    int add = (t >= off) ? sm.tk.sfx[t - off] : 0;
    __syncthreads();
    sm.tk.sfx[t] += add;
    __syncthreads();
  }
  int excl = sm.tk.sfx[t] - eq;
  int taken = 0;
  float part = 0.f;
#pragma unroll
  for (int i = 0; i < 8; ++i) {
    unsigned k = myk[i];
    bool keep;
    if (k > pref) keep = true;
    else if (k == pref) { keep = (excl + taken) < rem; taken++; }
    else keep = false;
    float f = keep ? key2f(k) : 0.f;
    int uu = t * 8 + i;
    sm.tk.hrow[uu] = f;
    part += f * Wix[uu];
  }
  sm.tk.red[t] = part;
  __syncthreads();   // also publishes hrow
  for (int off = 128; off > 0; off >>= 1) {
    if (t < off) sm.tk.red[t] += sm.tk.red[t + off];
    __syncthreads();
  }
  float S = sm.tk.red[0];
  const int w = t >> 6, l = t & 63;
  for (int o = w; o < OUT_N; o += 4) {
    float acc = 0.f;
    const float* wr = Wex + (size_t)o * HID;
#pragma unroll
    for (int q = 0; q < HID / 64; ++q) acc += sm.tk.hrow[l + 64 * q] * wr[l + 64 * q];
    for (int off = 32; off > 0; off >>= 1) acc += __shfl_down(acc, off, 64);
    if (l == 0) out[(size_t)b * OUT_N + o] = acc - Wei[o] * S + bo[o];
  }
}

// ---------- cooperative mega-kernel: all phases, grid.sync() between ----------
__global__ __launch_bounds__(256, 4) void mega_kernel(
    const float* x, const float* ctx, const float* W1, const float* b1,
    const float* segW1, const float* maskW1, const float* maskS1,
    const float* W2, const float* b2, const float* segW2,
    const float* maskW2, const float* maskS2, const float* Wex,
    const float* Wix, const float* Wei, const float* bo, float* outp,
    float* xT, float* ctxT, float* y1T, float* gate2T, float* y2T) {
  cg::grid_group grid = cg::this_grid();
  __shared__ SMem sm;
  transpose_phase(sm, x, xT, ctx, ctxT);
  grid.sync();
  dendff_phase(sm, W1, maskW1, b1, segW1, maskS1, segW2, maskS2, xT, ctxT, y1T, gate2T);
  grid.sync();
  if (blockIdx.x < B_SZ) topk_phase(sm, y1T, y1T);
  grid.sync();
  ff2_phase(sm, W2, maskW2, b2, y1T, gate2T, y2T);
  grid.sync();
  if (blockIdx.x < B_SZ) topkout_phase(sm, y2T, Wex, Wix, Wei, bo, outp);
}

// ---------- fallback wrappers (same phase code, separate launches) ----------
__global__ __launch_bounds__(256) void transpose_fb(const float* x, float* xT,
                                                    const float* ctx, float* ctxT) {
  __shared__ SMem sm;
  transpose_phase(sm, x, xT, ctx, ctxT);
}
__global__ __launch_bounds__(256, 4) void dendff_fb(
    const float* W1, const float* maskW1, const float* b1,
    const float* segW1, const float* maskS1, const float* segW2, const float* maskS2,
    const float* xT, const float* ctxT, float* y1T, float* gate2T) {
  __shared__ SMem sm;
  dendff_phase(sm, W1, maskW1, b1, segW1, maskS1, segW2, maskS2, xT, ctxT, y1T, gate2T);
}
__global__ __launch_bounds__(256) void topk_fb(const float* yT, float* dst) {
  __shared__ SMem sm;
  topk_phase(sm, yT, dst);
}
__global__ __launch_bounds__(256, 4) void ff2_fb(
    const float* W2, const float* maskW2, const float* b2,
    const float* h1T, const float* gate2T, float* y2T) {
  __shared__ SMem sm;
  ff2_phase(sm, W2, maskW2, b2, h1T, gate2T, y2T);
}
__global__ __launch_bounds__(256) void topkout_fb(
    const float* yT, const float* Wex, const float* Wix,
    const float* Wei, const float* bo, float* out) {
  __shared__ SMem sm;
  topkout_phase(sm, yT, Wex, Wix, Wei, bo, out);
}

extern "C" void kernel_launch(void* const* d_in, const int* in_sizes, int n_in,
                              void* d_out, int out_size, void* d_ws, size_t ws_size,
                              hipStream_t stream) {
  const float* x      = (const float*)d_in[0];
  const float* ctx    = (const float*)d_in[1];
  const float* W1     = (const float*)d_in[2];
  const float* b1     = (const float*)d_in[3];
  const float* segW1  = (const float*)d_in[4];
  const float* maskW1 = (const float*)d_in[5];
  const float* maskS1 = (const float*)d_in[6];
  const float* W2     = (const float*)d_in[7];
  const float* b2     = (const float*)d_in[8];
  const float* segW2  = (const float*)d_in[9];
  const float* maskW2 = (const float*)d_in[10];
  const float* maskS2 = (const float*)d_in[11];
  const float* Wex    = (const float*)d_in[12];
  const float* Wix    = (const float*)d_in[13];
  const float* Wei    = (const float*)d_in[14];
  const float* bo     = (const float*)d_in[15];
  float* outp = (float*)d_out;
  float* ws = (float*)d_ws;

  float* xT     = ws;             // 524288 floats
  float* ctxT   = ws + 524288;    // 262144
  float* y1T    = ws + 786432;    // 524288 (becomes h1T in place)
  float* gate2T = ws + 1310720;   // 524288
  float* y2T    = ws + 1835008;   // 524288  — total ~9.4 MB

  void* args[22] = {
    (void*)&x, (void*)&ctx, (void*)&W1, (void*)&b1, (void*)&segW1, (void*)&maskW1,
    (void*)&maskS1, (void*)&W2, (void*)&b2, (void*)&segW2, (void*)&maskW2,
    (void*)&maskS2, (void*)&Wex, (void*)&Wix, (void*)&Wei, (void*)&bo, (void*)&outp,
    (void*)&xT, (void*)&ctxT, (void*)&y1T, (void*)&gate2T, (void*)&y2T
  };
  hipError_t e = hipLaunchCooperativeKernel(mega_kernel, dim3(1024), dim3(256),
                                            args, 0u, stream);
  if (e != hipSuccess) {
    // fallback: same phases as 5 plain launches
    transpose_fb<<<768, 256, 0, stream>>>(x, xT, ctx, ctxT);
    dendff_fb<<<1024, 256, 0, stream>>>(W1, maskW1, b1, segW1, maskS1, segW2, maskS2,
                                        xT, ctxT, y1T, gate2T);
    topk_fb<<<B_SZ, 256, 0, stream>>>(y1T, y1T);
    ff2_fb<<<1024, 256, 0, stream>>>(W2, maskW2, b2, y1T, gate2T, y2T);
    topkout_fb<<<B_SZ, 256, 0, stream>>>(y2T, Wex, Wix, Wei, bo, outp);
  }
}

// Round 8
// 497.192 us; speedup vs baseline: 2.3903x; 2.3903x over previous
//
#include <hip/hip_runtime.h>
#include <math.h>

#define B_SZ   256
#define D_IN   2048
#define HID    2048
#define NSEG   10
#define D_CTX  1024
#define OUT_N  100
#define KWIN   102
#define CAPF   128   // ff2: per-1024-chunk pair cap (mean 51.2, +11 sigma)
#define SUBF   512   // dendff: floats per DMA-staged sub-chunk
#define CAPD   80    // dendff: per-sub pair cap (mean 25.6, +11 sigma)

typedef float f32x4 __attribute__((ext_vector_type(4)));

// non-temporal 16B load: weight/mask streams must not evict L2-resident activations
__device__ __forceinline__ f32x4 ntld4(const float* p) {
  return __builtin_nontemporal_load((const f32x4*)p);
}

// async global->LDS DMA, 16B/lane: per-lane global src, wave-uniform LDS base;
// lane t's 16B lands at ldsbase + t*16 (m97/m104 semantics). Costs zero VGPRs.
__device__ __forceinline__ void gl_lds(const float* g, float* l) {
  __builtin_amdgcn_global_load_lds(
      (const __attribute__((address_space(1))) void*)g,
      (__attribute__((address_space(3))) void*)l, 16, 0, 0);
}

// ---------- sortable-key helpers for exact fp32 top-k ----------
__device__ __forceinline__ unsigned f2key(float f) {
  unsigned b = __float_as_uint(f);
  return (b & 0x80000000u) ? ~b : (b | 0x80000000u);
}
__device__ __forceinline__ float key2f(unsigned k) {
  return (k & 0x80000000u) ? __uint_as_float(k & 0x7FFFFFFFu) : __uint_as_float(~k);
}

// ---------- combined transpose for x and ctx (one launch) ----------
__global__ __launch_bounds__(256) void transpose2_k(const float* __restrict__ xsrc,
                                                    float* __restrict__ xdst,
                                                    const float* __restrict__ csrc,
                                                    float* __restrict__ cdst) {
  __shared__ float tile[32][33];
  int bid = blockIdx.x;
  const float* src; float* dst; int cols;
  const int NX = (D_IN / 32) * (B_SZ / 32);  // 512
  if (bid < NX) { src = xsrc; dst = xdst; cols = D_IN; }
  else { bid -= NX; src = csrc; dst = cdst; cols = D_CTX; }
  int nbx = cols / 32;
  int bx = bid % nbx, by = bid / nbx;
  int c0 = bx * 32, r0 = by * 32;
  int tx = threadIdx.x & 31, ty = threadIdx.x >> 5;
  for (int i = ty; i < 32; i += 8)
    tile[i][tx] = src[(r0 + i) * cols + (c0 + tx)];
  __syncthreads();
  for (int i = ty; i < 32; i += 8)
    dst[(c0 + i) * B_SZ + (r0 + tx)] = tile[tx][i];
}

// ---------- sparse dot, unroll-8 (8 outstanding 1KB loads/wave) ----------
__device__ __forceinline__ void gather_dot(const float* __restrict__ src,
                                           const float2* pairs, int cnt,
                                           int t4, float out4[4]) {
  float acc[4][4];
#pragma unroll
  for (int s = 0; s < 4; ++s)
#pragma unroll
    for (int i = 0; i < 4; ++i) acc[s][i] = 0.f;
  int j = 0;
  for (; j + 8 <= cnt; j += 8) {
#pragma unroll
    for (int s = 0; s < 8; ++s) {
      float2 p = pairs[j + s];
      const f32x4 cv = *(const f32x4*)(src + (__float_as_int(p.y) << 8) + t4);
      acc[s & 3][0] += cv.x * p.x; acc[s & 3][1] += cv.y * p.x;
      acc[s & 3][2] += cv.z * p.x; acc[s & 3][3] += cv.w * p.x;
    }
  }
  for (; j < cnt; ++j) {
    float2 p = pairs[j];
    const f32x4 cv = *(const f32x4*)(src + (__float_as_int(p.y) << 8) + t4);
    acc[0][0] += cv.x * p.x; acc[0][1] += cv.y * p.x;
    acc[0][2] += cv.z * p.x; acc[0][3] += cv.w * p.x;
  }
#pragma unroll
  for (int i = 0; i < 4; ++i)
    out4[i] = (acc[0][i] + acc[1][i]) + (acc[2][i] + acc[3][i]);
}

// ---------- issue-only DMA stage of one 512-float (w,m) sub-chunk into LDS ----------
__device__ __forceinline__ void stage_sub(const float* __restrict__ wp,
                                          const float* __restrict__ mp,
                                          float* sw, float* sm) {
  const int t = threadIdx.x & 63;
  gl_lds(wp + 4 * t, sw);              // floats [0,256)
  gl_lds(wp + 256 + 4 * t, sw + 256);  // floats [256,512)
  gl_lds(mp + 4 * t, sm);
  gl_lds(mp + 256 + 4 * t, sm + 256);
}

// ---------- ballot-compact a staged 512-float sub-chunk (LDS source) ----------
__device__ __forceinline__ int compact_staged(const float* sw, const float* sm,
                                              int coff, float2* pairs) {
  const int t = threadIdx.x & 63;
  const unsigned long long below = (1ull << t) - 1ull;
  __builtin_amdgcn_wave_barrier();   // don't migrate pair writes above prior pair reads
  int base = 0;
#pragma unroll
  for (int i = 0; i < 2; ++i) {
    const int e = t + 64 * i;
    f32x4 ww = *(const f32x4*)(sw + 4 * e);   // ds_read_b128
    f32x4 mm = *(const f32x4*)(sm + 4 * e);
    const float wv[4] = {ww.x, ww.y, ww.z, ww.w};
    const float mv[4] = {mm.x, mm.y, mm.z, mm.w};
    const int c = (e << 2) + coff;
#pragma unroll
    for (int j = 0; j < 4; ++j) {
      bool nz = (mv[j] != 0.f);
      unsigned long long bal = __ballot(nz);
      if (nz) {
        int pos = base + (int)__popcll(bal & below);
        if (pos < CAPD) pairs[pos] = make_float2(wv[j], __int_as_float(c + j));
      }
      base += (int)__popcll(bal);
    }
  }
  __builtin_amdgcn_wave_barrier();
  return base > CAPD ? CAPD : base;
}

// ---------- fused dendrites + FF1, DMA-pipelined, double-buffered staging ----------
// 2048 blocks, 2 rows/block, 2 waves/row (segs 0-4 / 5-9; L1 rows add FF1 half-row).
// Per phase: compact staged sub k (LDS buf k&1) -> issue DMA of sub k+1 into buf^1
// -> gather k (L2) -> vmcnt(0). Each SEGMENT = 2 subs: accumulate dseg over both,
// update argmax only after the odd sub (r7 bug: per-sub argmax broke semantics).
__global__ __launch_bounds__(256, 4) void dendff_kernel(
    const float* __restrict__ W1, const float* __restrict__ maskW1, const float* __restrict__ b1,
    const float* __restrict__ segW1, const float* __restrict__ maskS1,
    const float* __restrict__ segW2, const float* __restrict__ maskS2,
    const float* __restrict__ xT, const float* __restrict__ ctxT,
    float* __restrict__ y1T, float* __restrict__ gate2T) {
  __shared__ __align__(16) float stw[4][2][SUBF];
  __shared__ __align__(16) float stm[4][2][SUBF];
  __shared__ union {
    float2 pairs[4][CAPD];       // 2560 B (main loop)
    float exch[2][64][13];       // 6656 B (epilogue; barrier-separated)
  } u;
  const int wave = threadIdx.x >> 6;
  const int t = threadIdx.x & 63, t4 = t * 4;
  const int pidx = wave >> 1;        // row-in-block
  const int half = wave & 1;         // 0 -> segs 0..4, 1 -> segs 5..9
  const int row = blockIdx.x * 2 + pidx;       // 0..4095
  const bool isL1 = (row < HID);
  const int uu = isL1 ? row : (row - HID);
  const float* segW = (isL1 ? segW1 : segW2)
                      + (size_t)uu * NSEG * D_CTX + (size_t)half * 5 * D_CTX;
  const float* maskS = (isL1 ? maskS1 : maskS2)
                      + (size_t)uu * NSEG * D_CTX + (size_t)half * 5 * D_CTX;
  const float* ffW = W1 + (size_t)uu * D_IN + half * 1024;
  const float* ffM = maskW1 + (size_t)uu * D_IN + half * 1024;
  float2* pairs = u.pairs[wave];
  const int nsub = isL1 ? 12 : 10;   // 10 seg-subs (+2 FF subs for L1); wave-uniform

  float bestA[4] = {-1.f, -1.f, -1.f, -1.f};
  float chosen[4] = {0.f, 0.f, 0.f, 0.f};
  float ffp[4] = {0.f, 0.f, 0.f, 0.f};
  float dseg[4] = {0.f, 0.f, 0.f, 0.f};

  stage_sub(segW, maskS, stw[wave][0], stm[wave][0]);  // sub 0 -> buf 0
  asm volatile("s_waitcnt vmcnt(0)" ::: "memory");     // DMA landed in LDS
#pragma unroll 1
  for (int k = 0; k < nsub; ++k) {
    const bool isFF = (k >= 10);
    const int buf = k & 1;
    const int coff = isFF ? (half * 1024 + (k & 1) * SUBF) : ((k & 1) * SUBF);
    int cnt = compact_staged(stw[wave][buf], stm[wave][buf], coff, pairs);
    __builtin_amdgcn_sched_barrier(0);               // keep DMA issue below the ds_reads
    if (k + 1 < nsub) {                              // issue-only DMA of next sub -> buf^1
      const int kn = k + 1;
      const float* wp; const float* mp;
      if (kn < 10) {
        wp = segW + (kn >> 1) * D_CTX + (kn & 1) * SUBF;
        mp = maskS + (kn >> 1) * D_CTX + (kn & 1) * SUBF;
      } else {
        wp = ffW + (kn & 1) * SUBF;
        mp = ffM + (kn & 1) * SUBF;
      }
      stage_sub(wp, mp, stw[wave][buf ^ 1], stm[wave][buf ^ 1]);
    }
    float d[4];
    gather_dot(isFF ? xT : ctxT, pairs, cnt, t4, d); // L2 gather overlaps the DMA stream
    if (isFF) {
#pragma unroll
      for (int i = 0; i < 4; ++i) ffp[i] += d[i];
    } else if ((k & 1) == 0) {                       // even sub: start segment accumulator
#pragma unroll
      for (int i = 0; i < 4; ++i) dseg[i] = d[i];
    } else {                                         // odd sub: full segment dot ready
#pragma unroll
      for (int i = 0; i < 4; ++i) {
        float full = dseg[i] + d[i];
        float a = fabsf(full);
        if (a > bestA[i]) { bestA[i] = a; chosen[i] = full; }  // strict > = first occurrence
      }
    }
    asm volatile("s_waitcnt vmcnt(0)" ::: "memory"); // next sub resident in LDS
  }

  __syncthreads();   // all waves done with pairs (pairs/exch union safety)
  if (half) {
#pragma unroll
    for (int i = 0; i < 4; ++i) {
      u.exch[pidx][t][i] = bestA[i];
      u.exch[pidx][t][4 + i] = chosen[i];
      u.exch[pidx][t][8 + i] = ffp[i];
    }
  }
  __syncthreads();
  if (!half) {
#pragma unroll
    for (int i = 0; i < 4; ++i) {
      float a1 = u.exch[pidx][t][i];
      if (a1 > bestA[i]) chosen[i] = u.exch[pidx][t][4 + i];  // half-0 wins ties (lower seg)
      ffp[i] += u.exch[pidx][t][8 + i];
    }
    if (isL1) {
      float bb = b1[uu];
      float4 o;
      o.x = (ffp[0] + bb) / (1.f + expf(-chosen[0]));
      o.y = (ffp[1] + bb) / (1.f + expf(-chosen[1]));
      o.z = (ffp[2] + bb) / (1.f + expf(-chosen[2]));
      o.w = (ffp[3] + bb) / (1.f + expf(-chosen[3]));
      *(float4*)(y1T + (size_t)uu * B_SZ + t4) = o;
    } else {
      float4 g;
      g.x = 1.f / (1.f + expf(-chosen[0]));
      g.y = 1.f / (1.f + expf(-chosen[1]));
      g.z = 1.f / (1.f + expf(-chosen[2]));
      g.w = 1.f / (1.f + expf(-chosen[3]));
      *(float4*)(gate2T + (size_t)uu * B_SZ + t4) = g;
    }
  }
}

// ---------- ballot-compact a 1024-float (w,mask) chunk (global source; ff2) ----------
__device__ __forceinline__ int compact_pairs_1024(const float* __restrict__ wrow,
                                                  const float* __restrict__ mrow,
                                                  int coff, float2* pairs) {
  const int t = threadIdx.x & 63;
  const unsigned long long below = (1ull << t) - 1ull;
  __builtin_amdgcn_wave_barrier();
  int base = 0;
#pragma unroll
  for (int i = 0; i < 4; ++i) {
    const int e = t + 64 * i;
    f32x4 ww = ntld4(wrow + 4 * e);
    f32x4 mm = ntld4(mrow + 4 * e);
    const float wv[4] = {ww.x, ww.y, ww.z, ww.w};
    const float mv[4] = {mm.x, mm.y, mm.z, mm.w};
    const int c = (e << 2) + coff;
#pragma unroll
    for (int j = 0; j < 4; ++j) {
      bool nz = (mv[j] != 0.f);
      unsigned long long bal = __ballot(nz);
      if (nz) {
        int pos = base + (int)__popcll(bal & below);
        if (pos < CAPF) pairs[pos] = make_float2(wv[j], __int_as_float(c + j));
      }
      base += (int)__popcll(bal);
    }
  }
  __builtin_amdgcn_wave_barrier();
  return base > CAPF ? CAPF : base;
}

// ---------- FF2: 1024 blocks, 2 units/block, 2 waves/unit (half-row each) ----------
__global__ __launch_bounds__(256, 4) void ff2_kernel(
    const float* __restrict__ W2, const float* __restrict__ maskW2, const float* __restrict__ b2,
    const float* __restrict__ h1T, const float* __restrict__ gate2T, float* __restrict__ y2T) {
  __shared__ float2 pairs_s[4][CAPF];
  __shared__ float exch[2][64][5];
  const int wave = threadIdx.x >> 6;
  const int t = threadIdx.x & 63, t4 = t * 4;
  const int pidx = wave >> 1, half = wave & 1;
  const int u = blockIdx.x * 2 + pidx;
  const int off = half * 1024;
  int cnt = compact_pairs_1024(W2 + (size_t)u * HID + off,
                               maskW2 + (size_t)u * HID + off, off, pairs_s[wave]);
  float acc[4];
  gather_dot(h1T, pairs_s[wave], cnt, t4, acc);
  if (half) {
#pragma unroll
    for (int i = 0; i < 4; ++i) exch[pidx][t][i] = acc[i];
  }
  __syncthreads();
  if (!half) {
#pragma unroll
    for (int i = 0; i < 4; ++i) acc[i] += exch[pidx][t][i];
    float bb = b2[u];
    float4 g = *(const float4*)(gate2T + (size_t)u * B_SZ + t4);
    float4 o;
    o.x = (acc[0] + bb) * g.x; o.y = (acc[1] + bb) * g.y;
    o.z = (acc[2] + bb) * g.z; o.w = (acc[3] + bb) * g.w;
    *(float4*)(y2T + (size_t)u * B_SZ + t4) = o;
  }
}

// ---------- exact top-K per batch column of yT [HID][B]; radix select, stable ties ----------
__global__ __launch_bounds__(256) void topk_kernel(const float* __restrict__ yT,
                                                   float* __restrict__ dst, int mode) {
  const int b = blockIdx.x, t = threadIdx.x;
  __shared__ int hist[256];
  __shared__ int sfx[256];
  __shared__ unsigned sPref;
  __shared__ int sRem;
  unsigned myk[8];
#pragma unroll
  for (int i = 0; i < 8; ++i)
    myk[i] = f2key(yT[(size_t)(t * 8 + i) * B_SZ + b]);
  unsigned pref = 0;
  int rem = KWIN;
  for (int shift = 24; shift >= 0; shift -= 8) {
    hist[t] = 0;
    __syncthreads();
    unsigned hiMask = (shift == 24) ? 0u : (0xFFFFFFFFu << (shift + 8));
#pragma unroll
    for (int i = 0; i < 8; ++i) {
      unsigned k = myk[i];
      if ((k & hiMask) == pref) atomicAdd(&hist[(k >> shift) & 255], 1);
    }
    __syncthreads();
    sfx[t] = hist[t];
    __syncthreads();
    for (int off = 1; off < 256; off <<= 1) {
      int add = (t + off < 256) ? sfx[t + off] : 0;
      __syncthreads();
      sfx[t] += add;
      __syncthreads();
    }
    int s_incl = sfx[t];
    int s_excl = (t == 255) ? 0 : sfx[t + 1];
    if (s_incl >= rem && s_excl < rem) {
      sPref = pref | (((unsigned)t) << shift);
      sRem = rem - s_excl;
    }
    __syncthreads();
    pref = sPref;
    rem = sRem;
    __syncthreads();
  }
  int eq = 0;
#pragma unroll
  for (int i = 0; i < 8; ++i) eq += (myk[i] == pref) ? 1 : 0;
  sfx[t] = eq;
  __syncthreads();
  for (int off = 1; off < 256; off <<= 1) {
    int add = (t >= off) ? sfx[t - off] : 0;
    __syncthreads();
    sfx[t] += add;
    __syncthreads();
  }
  int excl = sfx[t] - eq;
  int taken = 0;
#pragma unroll
  for (int i = 0; i < 8; ++i) {
    unsigned k = myk[i];
    bool keep;
    if (k > pref) keep = true;
    else if (k == pref) { keep = (excl + taken) < rem; taken++; }
    else keep = false;
    float f = keep ? key2f(k) : 0.f;
    int uu = t * 8 + i;
    if (mode == 0) dst[(size_t)uu * B_SZ + b] = f;
    else dst[(size_t)b * HID + uu] = f;
  }
}

// ---------- fused topk2 + Dale output head ----------
__global__ __launch_bounds__(256) void topkout_kernel(
    const float* __restrict__ yT, const float* __restrict__ Wex, const float* __restrict__ Wix,
    const float* __restrict__ Wei, const float* __restrict__ bo, float* __restrict__ out) {
  const int b = blockIdx.x, t = threadIdx.x;
  __shared__ int hist[256];
  __shared__ int sfx[256];
  __shared__ unsigned sPref;
  __shared__ int sRem;
  __shared__ float hrow[HID];
  __shared__ float red[256];
  unsigned myk[8];
#pragma unroll
  for (int i = 0; i < 8; ++i)
    myk[i] = f2key(yT[(size_t)(t * 8 + i) * B_SZ + b]);
  unsigned pref = 0;
  int rem = KWIN;
  for (int shift = 24; shift >= 0; shift -= 8) {
    hist[t] = 0;
    __syncthreads();
    unsigned hiMask = (shift == 24) ? 0u : (0xFFFFFFFFu << (shift + 8));
#pragma unroll
    for (int i = 0; i < 8; ++i) {
      unsigned k = myk[i];
      if ((k & hiMask) == pref) atomicAdd(&hist[(k >> shift) & 255], 1);
    }
    __syncthreads();
    sfx[t] = hist[t];
    __syncthreads();
    for (int off = 1; off < 256; off <<= 1) {
      int add = (t + off < 256) ? sfx[t + off] : 0;
      __syncthreads();
      sfx[t] += add;
      __syncthreads();
    }
    int s_incl = sfx[t];
    int s_excl = (t == 255) ? 0 : sfx[t + 1];
    if (s_incl >= rem && s_excl < rem) {
      sPref = pref | (((unsigned)t) << shift);
      sRem = rem - s_excl;
    }
    __syncthreads();
    pref = sPref;
    rem = sRem;
    __syncthreads();
  }
  int eq = 0;
#pragma unroll
  for (int i = 0; i < 8; ++i) eq += (myk[i] == pref) ? 1 : 0;
  sfx[t] = eq;
  __syncthreads();
  for (int off = 1; off < 256; off <<= 1) {
    int add = (t >= off) ? sfx[t - off] : 0;
    __syncthreads();
    sfx[t] += add;
    __syncthreads();
  }
  int excl = sfx[t] - eq;
  int taken = 0;
  float part = 0.f;
#pragma unroll
  for (int i = 0; i < 8; ++i) {
    unsigned k = myk[i];
    bool keep;
    if (k > pref) keep = true;
    else if (k == pref) { keep = (excl + taken) < rem; taken++; }
    else keep = false;
    float f = keep ? key2f(k) : 0.f;
    int uu = t * 8 + i;
    hrow[uu] = f;
    part += f * Wix[uu];
  }
  red[t] = part;
  __syncthreads();   // also publishes hrow
  for (int off = 128; off > 0; off >>= 1) {
    if (t < off) red[t] += red[t + off];
    __syncthreads();
  }
  float S = red[0];
  const int w = t >> 6, l = t & 63;
  for (int o = w; o < OUT_N; o += 4) {
    float acc = 0.f;
    const float* wr = Wex + (size_t)o * HID;
#pragma unroll
    for (int q = 0; q < HID / 64; ++q) acc += hrow[l + 64 * q] * wr[l + 64 * q];
    for (int off = 32; off > 0; off >>= 1) acc += __shfl_down(acc, off, 64);
    if (l == 0) out[(size_t)b * OUT_N + o] = acc - Wei[o] * S + bo[o];
  }
}

extern "C" void kernel_launch(void* const* d_in, const int* in_sizes, int n_in,
                              void* d_out, int out_size, void* d_ws, size_t ws_size,
                              hipStream_t stream) {
  const float* x      = (const float*)d_in[0];
  const float* ctx    = (const float*)d_in[1];
  const float* W1     = (const float*)d_in[2];
  const float* b1     = (const float*)d_in[3];
  const float* segW1  = (const float*)d_in[4];
  const float* maskW1 = (const float*)d_in[5];
  const float* maskS1 = (const float*)d_in[6];
  const float* W2     = (const float*)d_in[7];
  const float* b2     = (const float*)d_in[8];
  const float* segW2  = (const float*)d_in[9];
  const float* maskW2 = (const float*)d_in[10];
  const float* maskS2 = (const float*)d_in[11];
  const float* Wex    = (const float*)d_in[12];
  const float* Wix    = (const float*)d_in[13];
  const float* Wei    = (const float*)d_in[14];
  const float* bo     = (const float*)d_in[15];
  float* out = (float*)d_out;
  float* ws = (float*)d_ws;

  float* xT     = ws;             // 524288 floats
  float* ctxT   = ws + 524288;    // 262144
  float* y1T    = ws + 786432;    // 524288 (becomes h1T in place)
  float* gate2T = ws + 1310720;   // 524288
  float* y2T    = ws + 1835008;   // 524288  — total ~9.4 MB

  transpose2_k<<<768, 256, 0, stream>>>(x, xT, ctx, ctxT);
  dendff_kernel<<<2 * HID / 2, 256, 0, stream>>>(W1, maskW1, b1, segW1, maskS1,
                                                 segW2, maskS2, xT, ctxT, y1T, gate2T);
  topk_kernel<<<B_SZ, 256, 0, stream>>>(y1T, y1T, 0);   // h1T in place
  ff2_kernel<<<HID / 2, 256, 0, stream>>>(W2, maskW2, b2, y1T, gate2T, y2T);
  topkout_kernel<<<B_SZ, 256, 0, stream>>>(y2T, Wex, Wix, Wei, bo, out);
}